// Round 12
// baseline (458.840 us; speedup 1.0000x reference)
//
#include <hip/hip_runtime.h>
#include <hip/hip_cooperative_groups.h>
#include <cstdint>

namespace cg = cooperative_groups;

using u16 = unsigned short;
typedef __bf16 bf16x8 __attribute__((ext_vector_type(8)));
typedef __bf16 bf16x4 __attribute__((ext_vector_type(4)));
typedef float f32x4 __attribute__((ext_vector_type(4)));

#define MFMA16(a, b, c) __builtin_amdgcn_mfma_f32_16x16x32_bf16((a), (b), (c), 0, 0, 0)

__device__ __forceinline__ u16 f2bf(float f) {
  union { float f; uint32_t u; } c; c.f = f;
  uint32_t u = c.u;
  u += 0x7fffu + ((u >> 16) & 1u);   // RNE
  return (u16)(u >> 16);
}

#if __has_builtin(__builtin_amdgcn_global_load_lds)
#define GLOAD_LDS16(g, l)                                                      \
  __builtin_amdgcn_global_load_lds(                                            \
      (__attribute__((address_space(1))) void*)(g),                            \
      (__attribute__((address_space(3))) void*)(l), 16, 0, 0)
#else
#define GLOAD_LDS16(g, l) do { *(uint4*)(l) = *(const uint4*)(g); } while (0)
#endif

// ======================= fused cooperative kernel ==========================
// 4 phases separated by grid syncs; every phase is a grid-stride loop over
// 512 virtual blocks so any physical grid works.
__global__ __launch_bounds__(256, 2) void fused(
    const float* __restrict__ x, const float* __restrict__ w_qkv,
    const float* __restrict__ b_qkv, const float* __restrict__ w_out,
    const float* __restrict__ b_out, float* __restrict__ out,
    u16* __restrict__ xb, u16* __restrict__ wqT, u16* __restrict__ woT,
    u16* __restrict__ qb, u16* __restrict__ kb, u16* __restrict__ vb,
    u16* __restrict__ ao) {
  const int S = 2048;
  const int tid = threadIdx.x;
  const int lane = tid & 63, w = tid >> 6;
  const int quad = lane >> 4, l16 = lane & 15;

  __shared__ __align__(16) u16 smem[24576];  // 48 KB, repartitioned per phase
  cg::grid_group grid = cg::this_grid();

  // ================= phase 0: prep =================
  for (int v = blockIdx.x; v < 8192; v += gridDim.x) {
    if (v < 4096) {
      int i = (v * 256 + tid) * 4;
      float4 vv = *(const float4*)&x[i];
      ushort4 p;
      p.x = f2bf(vv.x); p.y = f2bf(vv.y); p.z = f2bf(vv.z); p.w = f2bf(vv.w);
      *(ushort4*)&xb[i] = p;
    } else {
      float* tile = (float*)smem;  // [32][33]
      int t = v - 4096;
      const float* in;
      u16* outp;
      int C, bx, by;
      if (t < 3072) { in = w_qkv; outp = wqT; C = 3072; bx = (t % 96) * 32; by = (t / 96) * 32; }
      else { t -= 3072; in = w_out; outp = woT; C = 1024; bx = (t % 32) * 32; by = (t / 32) * 32; }
      const int tx = tid & 31, ty = tid >> 5;
      __syncthreads();
#pragma unroll
      for (int r2 = 0; r2 < 4; ++r2)
        tile[(ty + r2 * 8) * 33 + tx] = in[(size_t)(by + ty + r2 * 8) * C + bx + tx];
      __syncthreads();
#pragma unroll
      for (int r2 = 0; r2 < 4; ++r2)
        outp[(size_t)(bx + ty + r2 * 8) * 1024 + by + tx] = f2bf(tile[tx * 33 + ty + r2 * 8]);
    }
  }
  __threadfence();
  grid.sync();
  __threadfence();

  // ============ phase 1: gemm_qkv 128x192, 512 virtual blocks ==============
  for (int p = blockIdx.x; p < 512; p += gridDim.x) {
    u16* As = smem;          // 128*32 u16 (8 KB)
    u16* Bs = smem + 4096;   // 192*32 u16 (12 KB)
    const int m0 = (p & 31) * 128;
    const int n0 = (p >> 5) * 192;
    const int wr = w >> 1, wc = w & 1;

    f32x4 acc[4][6] = {};

    const int r0 = tid >> 2, p0 = tid & 3;
    const int c8 = p0 ^ ((r0 >> 1) & 3);
    const u16* ga0 = xb + (size_t)(m0 + r0) * 1024 + c8 * 8;
    const u16* ga1 = ga0 + (size_t)64 * 1024;
    const u16* gb0 = wqT + (size_t)(n0 + r0) * 1024 + c8 * 8;
    const u16* gb1 = gb0 + (size_t)64 * 1024;
    const u16* gb2 = gb0 + (size_t)128 * 1024;
    u16* la0 = &As[tid * 8];
    u16* la1 = &As[(tid + 256) * 8];
    u16* lb0 = &Bs[tid * 8];
    u16* lb1 = &Bs[(tid + 256) * 8];
    u16* lb2 = &Bs[(tid + 512) * 8];

    int aoff[4], boff[6];
#pragma unroll
    for (int i = 0; i < 4; ++i) {
      int ra = wr * 64 + i * 16 + l16;
      aoff[i] = (ra * 4 + (quad ^ ((ra >> 1) & 3))) * 8;
    }
#pragma unroll
    for (int j = 0; j < 6; ++j) {
      int rb = wc * 96 + j * 16 + l16;
      boff[j] = (rb * 4 + (quad ^ ((rb >> 1) & 3))) * 8;
    }

    for (int kt = 0; kt < 32; ++kt) {
      __syncthreads();
      const int kk = kt << 5;
      GLOAD_LDS16(ga0 + kk, la0);
      GLOAD_LDS16(ga1 + kk, la1);
      GLOAD_LDS16(gb0 + kk, lb0);
      GLOAD_LDS16(gb1 + kk, lb1);
      GLOAD_LDS16(gb2 + kk, lb2);
      __syncthreads();
      bf16x8 af[4], bfr[6];
#pragma unroll
      for (int i = 0; i < 4; ++i) af[i] = *(const bf16x8*)&As[aoff[i]];
#pragma unroll
      for (int j = 0; j < 6; ++j) bfr[j] = *(const bf16x8*)&Bs[boff[j]];
#pragma unroll
      for (int i = 0; i < 4; ++i)
#pragma unroll
        for (int j = 0; j < 6; ++j)
          acc[i][j] = MFMA16(af[i], bfr[j], acc[i][j]);
    }

#pragma unroll
    for (int i = 0; i < 4; ++i) {
      const int mb = m0 + wr * 64 + i * 16 + quad * 4;
#pragma unroll
      for (int j = 0; j < 6; ++j) {
        const int n = n0 + wc * 96 + j * 16 + l16;
        const float bv = b_qkv[n];
        const int which = n >> 10;      // wave-uniform per (wc,j)
        const int hn = n & 1023;
        const int hh = hn >> 6, d = hn & 63;
        const int bb = mb >> 11, s = mb & 2047;
        const int bh = bb * 16 + hh;
        if (which == 2) {
          ushort4 pk;
          pk.x = f2bf(acc[i][j][0] + bv);
          pk.y = f2bf(acc[i][j][1] + bv);
          pk.z = f2bf(acc[i][j][2] + bv);
          pk.w = f2bf(acc[i][j][3] + bv);
          *(ushort4*)&vb[((size_t)bh * 64 + d) * S + s] = pk;  // V transposed
        } else {
          const float sc = (which == 0) ? 0.18033688f : 1.0f;  // 0.125*log2e
          u16* dst = (which == 0) ? qb : kb;
#pragma unroll
          for (int r = 0; r < 4; ++r)
            dst[((size_t)bh * S + s + r) * 64 + d] = f2bf((acc[i][j][r] + bv) * sc);
        }
      }
    }
  }
  __threadfence();
  grid.sync();
  __threadfence();

  // ============ phase 2: flash attention (R4 body), 512 virtual blocks =====
  for (int p = blockIdx.x; p < 512; p += gridDim.x) {
    u16* KsB = smem;            // [2][4096]
    u16* VsB = smem + 8192;     // [2][4096]
    u16* PsB = smem + 16384;    // [4][2048]
    const int ah = p & 15, ab = (p >> 4) & 1, qblk = p >> 5;
    const int bh = ab * 16 + ah;

    const int q0 = qblk * 128 + w * 32;
    const u16* qp = qb + ((size_t)bh * S + q0 + l16) * 64 + quad * 8;
    const bf16x8 qf00 = *(const bf16x8*)qp;
    const bf16x8 qf01 = *(const bf16x8*)(qp + 32);
    const bf16x8 qf10 = *(const bf16x8*)(qp + 1024);
    const bf16x8 qf11 = *(const bf16x8*)(qp + 1024 + 32);

    f32x4 accO0[4] = {}, accO1[4] = {};
    f32x4 accL0 = {}, accL1 = {};

    bf16x8 ones;
#pragma unroll
    for (int i = 0; i < 8; ++i) ones[i] = (__bf16)1.0f;

    const u16* kbase = kb + (size_t)bh * S * 64;
    const u16* vbase = vb + (size_t)bh * 64 * S;

    const int sr0 = tid >> 3, sp0 = tid & 7;
    const int c8s = sp0 ^ (sr0 & 7);
    const u16* kS0 = kbase + (size_t)sr0 * 64 + c8s * 8;
    const u16* kS1 = kbase + (size_t)(sr0 + 32) * 64 + c8s * 8;
    const u16* vS0 = vbase + (size_t)sr0 * S + c8s * 8;
    const u16* vS1 = vbase + (size_t)(sr0 + 32) * S + c8s * 8;

    int koff[4][2];
#pragma unroll
    for (int ct = 0; ct < 4; ++ct) {
      int row = ct * 16 + l16;
      koff[ct][0] = (row * 8 + (quad ^ (row & 7))) * 8;
      koff[ct][1] = (row * 8 + ((quad + 4) ^ (row & 7))) * 8;
    }
    u16* Pw0 = &PsB[w * 2048 + l16 * 64];
    u16* Pw1 = Pw0 + 1024;
    int pgx[4];
#pragma unroll
    for (int ct = 0; ct < 4; ++ct) pgx[ct] = ((ct * 4 + quad) ^ l16) * 4;
    const int pr0 = ((quad * 2) ^ l16) * 4;

    __syncthreads();  // buffers may still be read by other waves (prev iter)
    GLOAD_LDS16(kS0, &KsB[tid * 8]);
    GLOAD_LDS16(kS1, &KsB[tid * 8 + 2048]);
    GLOAD_LDS16(vS0, &VsB[tid * 8]);
    GLOAD_LDS16(vS1, &VsB[tid * 8 + 2048]);

    for (int kt = 0; kt < S / 64; ++kt) {
      const int cur = kt & 1;
      __syncthreads();
      if (kt + 1 < S / 64) {
        const int nb = cur ^ 1;
        GLOAD_LDS16(kS0 + (size_t)(kt + 1) * 4096, &KsB[nb * 4096 + tid * 8]);
        GLOAD_LDS16(kS1 + (size_t)(kt + 1) * 4096, &KsB[nb * 4096 + tid * 8 + 2048]);
        GLOAD_LDS16(vS0 + (kt + 1) * 64, &VsB[nb * 4096 + tid * 8]);
        GLOAD_LDS16(vS1 + (kt + 1) * 64, &VsB[nb * 4096 + tid * 8 + 2048]);
      }
      const u16* Kc = KsB + cur * 4096;
      const u16* Vc = VsB + cur * 4096;

      bf16x8 kf0[4], kf1[4];
#pragma unroll
      for (int ct = 0; ct < 4; ++ct) {
        kf0[ct] = *(const bf16x8*)&Kc[koff[ct][0]];
        kf1[ct] = *(const bf16x8*)&Kc[koff[ct][1]];
      }
      f32x4 s0[4] = {}, s1[4] = {};
#pragma unroll
      for (int ct = 0; ct < 4; ++ct) {
        s0[ct] = MFMA16(kf0[ct], qf00, s0[ct]);
        s0[ct] = MFMA16(kf1[ct], qf01, s0[ct]);
        s1[ct] = MFMA16(kf0[ct], qf10, s1[ct]);
        s1[ct] = MFMA16(kf1[ct], qf11, s1[ct]);
      }

#pragma unroll
      for (int ct = 0; ct < 4; ++ct)
#pragma unroll
        for (int r = 0; r < 4; ++r) {
          s0[ct][r] = __builtin_amdgcn_exp2f(s0[ct][r]);
          s1[ct][r] = __builtin_amdgcn_exp2f(s1[ct][r]);
        }

#pragma unroll
      for (int ct = 0; ct < 4; ++ct) {
        bf16x4 a = {(__bf16)s0[ct][0], (__bf16)s0[ct][1],
                    (__bf16)s0[ct][2], (__bf16)s0[ct][3]};
        *(bf16x4*)&Pw0[pgx[ct]] = a;
        bf16x4 c = {(__bf16)s1[ct][0], (__bf16)s1[ct][1],
                    (__bf16)s1[ct][2], (__bf16)s1[ct][3]};
        *(bf16x4*)&Pw1[pgx[ct]] = c;
      }

      bf16x4 t0 = *(const bf16x4*)&Pw0[pr0];
      bf16x4 t1 = *(const bf16x4*)&Pw0[pr0 ^ 4];
      bf16x4 t2 = *(const bf16x4*)&Pw0[pr0 ^ 32];
      bf16x4 t3 = *(const bf16x4*)&Pw0[pr0 ^ 36];
      bf16x8 pf00 = __builtin_shufflevector(t0, t1, 0, 1, 2, 3, 4, 5, 6, 7);
      bf16x8 pf01 = __builtin_shufflevector(t2, t3, 0, 1, 2, 3, 4, 5, 6, 7);
      t0 = *(const bf16x4*)&Pw1[pr0];
      t1 = *(const bf16x4*)&Pw1[pr0 ^ 4];
      t2 = *(const bf16x4*)&Pw1[pr0 ^ 32];
      t3 = *(const bf16x4*)&Pw1[pr0 ^ 36];
      bf16x8 pf10 = __builtin_shufflevector(t0, t1, 0, 1, 2, 3, 4, 5, 6, 7);
      bf16x8 pf11 = __builtin_shufflevector(t2, t3, 0, 1, 2, 3, 4, 5, 6, 7);

      accL0 = MFMA16(ones, pf00, accL0);
      accL0 = MFMA16(ones, pf01, accL0);
      accL1 = MFMA16(ones, pf10, accL1);
      accL1 = MFMA16(ones, pf11, accL1);

#pragma unroll
      for (int ct = 0; ct < 4; ++ct) {
        bf16x8 vf0 = *(const bf16x8*)&Vc[koff[ct][0]];
        bf16x8 vf1 = *(const bf16x8*)&Vc[koff[ct][1]];
        accO0[ct] = MFMA16(vf0, pf00, accO0[ct]);
        accO0[ct] = MFMA16(vf1, pf01, accO0[ct]);
        accO1[ct] = MFMA16(vf0, pf10, accO1[ct]);
        accO1[ct] = MFMA16(vf1, pf11, accO1[ct]);
      }
    }

    const float inv0 = 1.f / accL0[0], inv1 = 1.f / accL1[0];
    const int s0r = q0 + l16, s1r = q0 + 16 + l16;
#pragma unroll
    for (int ct = 0; ct < 4; ++ct) {
      ushort4 pk;
      pk.x = f2bf(accO0[ct][0] * inv0);
      pk.y = f2bf(accO0[ct][1] * inv0);
      pk.z = f2bf(accO0[ct][2] * inv0);
      pk.w = f2bf(accO0[ct][3] * inv0);
      *(ushort4*)&ao[(size_t)(ab * S + s0r) * 1024 + ah * 64 + ct * 16 + quad * 4] = pk;
      pk.x = f2bf(accO1[ct][0] * inv1);
      pk.y = f2bf(accO1[ct][1] * inv1);
      pk.z = f2bf(accO1[ct][2] * inv1);
      pk.w = f2bf(accO1[ct][3] * inv1);
      *(ushort4*)&ao[(size_t)(ab * S + s1r) * 1024 + ah * 64 + ct * 16 + quad * 4] = pk;
    }
  }
  __threadfence();
  grid.sync();
  __threadfence();

  // ============ phase 3: gemm_out 64x128, 512 virtual blocks ===============
  for (int p = blockIdx.x; p < 512; p += gridDim.x) {
    u16* As = smem;          // 64*32 u16
    u16* Bs = smem + 2048;   // 128*32 u16
    const int m0 = (p & 63) * 64;
    const int n0 = (p >> 6) * 128;
    const int wr = w >> 1, wc = w & 1;

    f32x4 acc[2][4] = {};

    const int r0 = tid >> 2, p0 = tid & 3;
    const int c8 = p0 ^ ((r0 >> 1) & 3);
    const u16* ga0 = ao + (size_t)(m0 + r0) * 1024 + c8 * 8;
    const u16* gb0 = woT + (size_t)(n0 + r0) * 1024 + c8 * 8;
    const u16* gb1 = gb0 + (size_t)64 * 1024;
    u16* la0 = &As[tid * 8];
    u16* lb0 = &Bs[tid * 8];
    u16* lb1 = &Bs[(tid + 256) * 8];

    int aoff[2], boff[4];
#pragma unroll
    for (int i = 0; i < 2; ++i) {
      int ra = wr * 32 + i * 16 + l16;
      aoff[i] = (ra * 4 + (quad ^ ((ra >> 1) & 3))) * 8;
    }
#pragma unroll
    for (int j = 0; j < 4; ++j) {
      int rb = wc * 64 + j * 16 + l16;
      boff[j] = (rb * 4 + (quad ^ ((rb >> 1) & 3))) * 8;
    }

    for (int kt = 0; kt < 32; ++kt) {
      __syncthreads();
      const int kk = kt << 5;
      GLOAD_LDS16(ga0 + kk, la0);
      GLOAD_LDS16(gb0 + kk, lb0);
      GLOAD_LDS16(gb1 + kk, lb1);
      __syncthreads();
      bf16x8 af[2], bfr[4];
#pragma unroll
      for (int i = 0; i < 2; ++i) af[i] = *(const bf16x8*)&As[aoff[i]];
#pragma unroll
      for (int j = 0; j < 4; ++j) bfr[j] = *(const bf16x8*)&Bs[boff[j]];
#pragma unroll
      for (int i = 0; i < 2; ++i)
#pragma unroll
        for (int j = 0; j < 4; ++j)
          acc[i][j] = MFMA16(af[i], bfr[j], acc[i][j]);
    }

#pragma unroll
    for (int i = 0; i < 2; ++i) {
      const int mb = m0 + wr * 32 + i * 16 + quad * 4;
#pragma unroll
      for (int j = 0; j < 4; ++j) {
        const int n = n0 + wc * 64 + j * 16 + l16;
        const float bv = b_out[n];
#pragma unroll
        for (int r = 0; r < 4; ++r)
          out[(size_t)(mb + r) * 1024 + n] = acc[i][j][r] + bv;
      }
    }
  }
}

// ==================== fallback kernels (R10, proven 183.8 us) ==============

__global__ __launch_bounds__(256) void prep(
    const float* __restrict__ x, const float* __restrict__ w_qkv,
    const float* __restrict__ w_out, u16* __restrict__ xb,
    u16* __restrict__ wqT, u16* __restrict__ woT) {
  const int bid = blockIdx.x, tid = threadIdx.x;
  if (bid < 4096) {
    int i = (bid * 256 + tid) * 4;
    float4 v = *(const float4*)&x[i];
    ushort4 p;
    p.x = f2bf(v.x); p.y = f2bf(v.y); p.z = f2bf(v.z); p.w = f2bf(v.w);
    *(ushort4*)&xb[i] = p;
    return;
  }
  __shared__ float tile[32][33];
  int t = bid - 4096;
  const float* in;
  u16* outp;
  int C, bx, by;
  if (t < 3072) { in = w_qkv; outp = wqT; C = 3072; bx = (t % 96) * 32; by = (t / 96) * 32; }
  else { t -= 3072; in = w_out; outp = woT; C = 1024; bx = (t % 32) * 32; by = (t / 32) * 32; }
  const int tx = tid & 31, ty = tid >> 5;
#pragma unroll
  for (int r2 = 0; r2 < 4; ++r2)
    tile[ty + r2 * 8][tx] = in[(size_t)(by + ty + r2 * 8) * C + bx + tx];
  __syncthreads();
#pragma unroll
  for (int r2 = 0; r2 < 4; ++r2)
    outp[(size_t)(bx + ty + r2 * 8) * 1024 + by + tx] = f2bf(tile[tx][ty + r2 * 8]);
}

__global__ __launch_bounds__(256, 3) void gemm_qkv(
    const u16* __restrict__ A, const u16* __restrict__ Bt,
    const float* __restrict__ bias,
    u16* __restrict__ qb, u16* __restrict__ kb, u16* __restrict__ vb,
    int M, int N, int K) {
  __shared__ u16 As[128 * 32];
  __shared__ u16 Bs[128 * 32];
  const int tid = threadIdx.x;
  const int m0 = blockIdx.x * 128;
  const int n0 = blockIdx.y * 128;
  const int lane = tid & 63, w = tid >> 6;
  const int quad = lane >> 4, l16 = lane & 15;
  const int wr = w >> 1, wc = w & 1;

  f32x4 acc[4][4] = {};

  const int r0 = tid >> 2, p0 = tid & 3;
  const int r1 = r0 + 64;
  const int c8 = p0 ^ ((r0 >> 1) & 3);
  const u16* ga0 = A + (size_t)(m0 + r0) * K + c8 * 8;
  const u16* ga1 = A + (size_t)(m0 + r1) * K + c8 * 8;
  const u16* gb0 = Bt + (size_t)(n0 + r0) * K + c8 * 8;
  const u16* gb1 = Bt + (size_t)(n0 + r1) * K + c8 * 8;
  u16* la0 = &As[tid * 8];
  u16* la1 = &As[(tid + 256) * 8];
  u16* lb0 = &Bs[tid * 8];
  u16* lb1 = &Bs[(tid + 256) * 8];

  int aoff[4], boff[4];
#pragma unroll
  for (int i = 0; i < 4; ++i) {
    int ra = wr * 64 + i * 16 + l16;
    aoff[i] = (ra * 4 + (quad ^ ((ra >> 1) & 3))) * 8;
    int rb = wc * 64 + i * 16 + l16;
    boff[i] = (rb * 4 + (quad ^ ((rb >> 1) & 3))) * 8;
  }

  const int nIter = K >> 5;
  for (int kt = 0; kt < nIter; ++kt) {
    __syncthreads();
    const int kk = kt << 5;
    GLOAD_LDS16(ga0 + kk, la0);
    GLOAD_LDS16(ga1 + kk, la1);
    GLOAD_LDS16(gb0 + kk, lb0);
    GLOAD_LDS16(gb1 + kk, lb1);
    __syncthreads();
    bf16x8 af[4], bfr[4];
#pragma unroll
    for (int i = 0; i < 4; ++i) af[i] = *(const bf16x8*)&As[aoff[i]];
#pragma unroll
    for (int j = 0; j < 4; ++j) bfr[j] = *(const bf16x8*)&Bs[boff[j]];
#pragma unroll
    for (int i = 0; i < 4; ++i)
#pragma unroll
      for (int j = 0; j < 4; ++j)
        acc[i][j] = MFMA16(af[i], bfr[j], acc[i][j]);
  }

  const int S = 2048, NH = 16;
#pragma unroll
  for (int i = 0; i < 4; ++i) {
    const int mb = m0 + wr * 64 + i * 16 + quad * 4;
#pragma unroll
    for (int j = 0; j < 4; ++j) {
      const int n = n0 + wc * 64 + j * 16 + l16;
      const float bv = bias[n];
      const int which = n >> 10;
      const int hn = n & 1023;
      const int h = hn >> 6, d = hn & 63;
      const int b = mb >> 11, s = mb & 2047;
      const int bh = b * NH + h;
      if (which == 2) {
        ushort4 pk;
        pk.x = f2bf(acc[i][j][0] + bv);
        pk.y = f2bf(acc[i][j][1] + bv);
        pk.z = f2bf(acc[i][j][2] + bv);
        pk.w = f2bf(acc[i][j][3] + bv);
        *(ushort4*)&vb[((size_t)bh * 64 + d) * S + s] = pk;
      } else {
        const float sc = (which == 0) ? 0.18033688f : 1.0f;
        u16* dst = (which == 0) ? qb : kb;
#pragma unroll
        for (int r = 0; r < 4; ++r)
          dst[((size_t)bh * S + s + r) * 64 + d] = f2bf((acc[i][j][r] + bv) * sc);
      }
    }
  }
}

__global__ __launch_bounds__(256, 2) void gemm_out(
    const u16* __restrict__ A, const u16* __restrict__ Bt,
    const float* __restrict__ bias, float* __restrict__ outf,
    int M, int N, int K) {
  __shared__ u16 As[64 * 32];
  __shared__ u16 Bs[128 * 32];
  const int tid = threadIdx.x;
  const int m0 = blockIdx.x * 64;
  const int n0 = blockIdx.y * 128;
  const int lane = tid & 63, w = tid >> 6;
  const int quad = lane >> 4, l16 = lane & 15;
  const int wr = w >> 1, wc = w & 1;

  f32x4 acc[2][4] = {};

  const int r0 = tid >> 2, p0 = tid & 3;
  const int c8 = p0 ^ ((r0 >> 1) & 3);
  const u16* ga0 = A + (size_t)(m0 + r0) * K + c8 * 8;
  const u16* gb0 = Bt + (size_t)(n0 + r0) * K + c8 * 8;
  const u16* gb1 = Bt + (size_t)(n0 + r0 + 64) * K + c8 * 8;
  u16* la0 = &As[tid * 8];
  u16* lb0 = &Bs[tid * 8];
  u16* lb1 = &Bs[(tid + 256) * 8];

  int aoff[2], boff[4];
#pragma unroll
  for (int i = 0; i < 2; ++i) {
    int ra = wr * 32 + i * 16 + l16;
    aoff[i] = (ra * 4 + (quad ^ ((ra >> 1) & 3))) * 8;
  }
#pragma unroll
  for (int j = 0; j < 4; ++j) {
    int rb = wc * 64 + j * 16 + l16;
    boff[j] = (rb * 4 + (quad ^ ((rb >> 1) & 3))) * 8;
  }

  const int nIter = K >> 5;
  for (int kt = 0; kt < nIter; ++kt) {
    __syncthreads();
    const int kk = kt << 5;
    GLOAD_LDS16(ga0 + kk, la0);
    GLOAD_LDS16(gb0 + kk, lb0);
    GLOAD_LDS16(gb1 + kk, lb1);
    __syncthreads();
    bf16x8 af[2], bfr[4];
#pragma unroll
    for (int i = 0; i < 2; ++i) af[i] = *(const bf16x8*)&As[aoff[i]];
#pragma unroll
    for (int j = 0; j < 4; ++j) bfr[j] = *(const bf16x8*)&Bs[boff[j]];
#pragma unroll
    for (int i = 0; i < 2; ++i)
#pragma unroll
      for (int j = 0; j < 4; ++j)
        acc[i][j] = MFMA16(af[i], bfr[j], acc[i][j]);
  }

#pragma unroll
  for (int i = 0; i < 2; ++i) {
    const int mb = m0 + wr * 32 + i * 16 + quad * 4;
#pragma unroll
    for (int j = 0; j < 4; ++j) {
      const int n = n0 + wc * 64 + j * 16 + l16;
      const float bv = bias[n];
#pragma unroll
      for (int r = 0; r < 4; ++r)
        outf[(size_t)(mb + r) * N + n] = acc[i][j][r] + bv;
    }
  }
}

__global__ __launch_bounds__(256, 2) void attn_fa(
    const u16* __restrict__ qg, const u16* __restrict__ kg,
    const u16* __restrict__ vg, u16* __restrict__ o) {
  const int S = 2048, NH = 16;
  const int h = blockIdx.x, b = blockIdx.y, qblk = blockIdx.z;
  const int bh = b * NH + h;
  const int tid = threadIdx.x, w = tid >> 6, lane = tid & 63;
  const int quad = lane >> 4, l16 = lane & 15;

  __shared__ u16 Ks[2][4096];
  __shared__ u16 Vs[2][4096];
  __shared__ u16 Ps[4][2048];

  const int q0 = qblk * 128 + w * 32;
  const u16* qp = qg + ((size_t)bh * S + q0 + l16) * 64 + quad * 8;
  const bf16x8 qf00 = *(const bf16x8*)qp;
  const bf16x8 qf01 = *(const bf16x8*)(qp + 32);
  const bf16x8 qf10 = *(const bf16x8*)(qp + 1024);
  const bf16x8 qf11 = *(const bf16x8*)(qp + 1024 + 32);

  f32x4 accO0[4] = {}, accO1[4] = {};
  f32x4 accL0 = {}, accL1 = {};

  bf16x8 ones;
#pragma unroll
  for (int i = 0; i < 8; ++i) ones[i] = (__bf16)1.0f;

  const u16* kbase = kg + (size_t)bh * S * 64;
  const u16* vbase = vg + (size_t)bh * 64 * S;

  const int sr0 = tid >> 3, sp0 = tid & 7;
  const int c8s = sp0 ^ (sr0 & 7);
  const u16* kS0 = kbase + (size_t)sr0 * 64 + c8s * 8;
  const u16* kS1 = kbase + (size_t)(sr0 + 32) * 64 + c8s * 8;
  const u16* vS0 = vbase + (size_t)sr0 * S + c8s * 8;
  const u16* vS1 = vbase + (size_t)(sr0 + 32) * S + c8s * 8;

  int koff[4][2];
#pragma unroll
  for (int ct = 0; ct < 4; ++ct) {
    int row = ct * 16 + l16;
    koff[ct][0] = (row * 8 + (quad ^ (row & 7))) * 8;
    koff[ct][1] = (row * 8 + ((quad + 4) ^ (row & 7))) * 8;
  }
  u16* Pw0 = &Ps[w][l16 * 64];
  u16* Pw1 = Pw0 + 1024;
  int pgx[4];
#pragma unroll
  for (int ct = 0; ct < 4; ++ct) pgx[ct] = ((ct * 4 + quad) ^ l16) * 4;
  const int pr0 = ((quad * 2) ^ l16) * 4;

  GLOAD_LDS16(kS0, &Ks[0][tid * 8]);
  GLOAD_LDS16(kS1, &Ks[0][tid * 8 + 2048]);
  GLOAD_LDS16(vS0, &Vs[0][tid * 8]);
  GLOAD_LDS16(vS1, &Vs[0][tid * 8 + 2048]);

  for (int kt = 0; kt < S / 64; ++kt) {
    const int cur = kt & 1;
    __syncthreads();
    if (kt + 1 < S / 64) {
      const int nb = cur ^ 1;
      GLOAD_LDS16(kS0 + (size_t)(kt + 1) * 4096, &Ks[nb][tid * 8]);
      GLOAD_LDS16(kS1 + (size_t)(kt + 1) * 4096, &Ks[nb][tid * 8 + 2048]);
      GLOAD_LDS16(vS0 + (kt + 1) * 64, &Vs[nb][tid * 8]);
      GLOAD_LDS16(vS1 + (kt + 1) * 64, &Vs[nb][tid * 8 + 2048]);
    }
    const u16* Kc = Ks[cur];
    const u16* Vc = Vs[cur];

    bf16x8 kf0[4], kf1[4];
#pragma unroll
    for (int ct = 0; ct < 4; ++ct) {
      kf0[ct] = *(const bf16x8*)&Kc[koff[ct][0]];
      kf1[ct] = *(const bf16x8*)&Kc[koff[ct][1]];
    }
    f32x4 s0[4] = {}, s1[4] = {};
#pragma unroll
    for (int ct = 0; ct < 4; ++ct) {
      s0[ct] = MFMA16(kf0[ct], qf00, s0[ct]);
      s0[ct] = MFMA16(kf1[ct], qf01, s0[ct]);
      s1[ct] = MFMA16(kf0[ct], qf10, s1[ct]);
      s1[ct] = MFMA16(kf1[ct], qf11, s1[ct]);
    }

#pragma unroll
    for (int ct = 0; ct < 4; ++ct)
#pragma unroll
      for (int r = 0; r < 4; ++r) {
        s0[ct][r] = __builtin_amdgcn_exp2f(s0[ct][r]);
        s1[ct][r] = __builtin_amdgcn_exp2f(s1[ct][r]);
      }

#pragma unroll
    for (int ct = 0; ct < 4; ++ct) {
      bf16x4 a = {(__bf16)s0[ct][0], (__bf16)s0[ct][1],
                  (__bf16)s0[ct][2], (__bf16)s0[ct][3]};
      *(bf16x4*)&Pw0[pgx[ct]] = a;
      bf16x4 c = {(__bf16)s1[ct][0], (__bf16)s1[ct][1],
                  (__bf16)s1[ct][2], (__bf16)s1[ct][3]};
      *(bf16x4*)&Pw1[pgx[ct]] = c;
    }

    bf16x4 t0 = *(const bf16x4*)&Pw0[pr0];
    bf16x4 t1 = *(const bf16x4*)&Pw0[pr0 ^ 4];
    bf16x4 t2 = *(const bf16x4*)&Pw0[pr0 ^ 32];
    bf16x4 t3 = *(const bf16x4*)&Pw0[pr0 ^ 36];
    bf16x8 pf00 = __builtin_shufflevector(t0, t1, 0, 1, 2, 3, 4, 5, 6, 7);
    bf16x8 pf01 = __builtin_shufflevector(t2, t3, 0, 1, 2, 3, 4, 5, 6, 7);
    t0 = *(const bf16x4*)&Pw1[pr0];
    t1 = *(const bf16x4*)&Pw1[pr0 ^ 4];
    t2 = *(const bf16x4*)&Pw1[pr0 ^ 32];
    t3 = *(const bf16x4*)&Pw1[pr0 ^ 36];
    bf16x8 pf10 = __builtin_shufflevector(t0, t1, 0, 1, 2, 3, 4, 5, 6, 7);
    bf16x8 pf11 = __builtin_shufflevector(t2, t3, 0, 1, 2, 3, 4, 5, 6, 7);

    accL0 = MFMA16(ones, pf00, accL0);
    accL0 = MFMA16(ones, pf01, accL0);
    accL1 = MFMA16(ones, pf10, accL1);
    accL1 = MFMA16(ones, pf11, accL1);

#pragma unroll
    for (int ct = 0; ct < 4; ++ct) {
      bf16x8 vf0 = *(const bf16x8*)&Vc[koff[ct][0]];
      bf16x8 vf1 = *(const bf16x8*)&Vc[koff[ct][1]];
      accO0[ct] = MFMA16(vf0, pf00, accO0[ct]);
      accO0[ct] = MFMA16(vf1, pf01, accO0[ct]);
      accO1[ct] = MFMA16(vf0, pf10, accO1[ct]);
      accO1[ct] = MFMA16(vf1, pf11, accO1[ct]);
    }
  }

  const float inv0 = 1.f / accL0[0], inv1 = 1.f / accL1[0];

  const int s0r = q0 + l16, s1r = q0 + 16 + l16;
#pragma unroll
  for (int ct = 0; ct < 4; ++ct) {
    ushort4 pk;
    pk.x = f2bf(accO0[ct][0] * inv0);
    pk.y = f2bf(accO0[ct][1] * inv0);
    pk.z = f2bf(accO0[ct][2] * inv0);
    pk.w = f2bf(accO0[ct][3] * inv0);
    *(ushort4*)&o[(size_t)(b * S + s0r) * 1024 + h * 64 + ct * 16 + quad * 4] = pk;
    pk.x = f2bf(accO1[ct][0] * inv1);
    pk.y = f2bf(accO1[ct][1] * inv1);
    pk.z = f2bf(accO1[ct][2] * inv1);
    pk.w = f2bf(accO1[ct][3] * inv1);
    *(ushort4*)&o[(size_t)(b * S + s1r) * 1024 + h * 64 + ct * 16 + quad * 4] = pk;
  }
}

// ---------------- launch ----------------

extern "C" void kernel_launch(void* const* d_in, const int* in_sizes, int n_in,
                              void* d_out, int out_size, void* d_ws, size_t ws_size,
                              hipStream_t stream) {
  const float* x = (const float*)d_in[0];
  const float* w_qkv = (const float*)d_in[1];
  const float* b_qkv = (const float*)d_in[2];
  const float* w_out = (const float*)d_in[3];
  const float* b_out = (const float*)d_in[4];
  float* out = (float*)d_out;

  u16* xb = (u16*)d_ws;                 // [4096,1024]
  u16* wqT = xb + 4096 * 1024;          // [3072,1024]
  u16* woT = wqT + 3072 * 1024;         // [1024,1024]
  u16* qb = woT + 1024 * 1024;          // [32,2048,64] (pre-scaled)
  u16* kb = qb + 4194304;               // [32,2048,64]
  u16* vb = kb + 4194304;               // [32,64,2048]
  u16* ao = vb + 4194304;               // [4096,1024]

  // Try cooperative fusion, sized by occupancy; fall back to the proven
  // 4-kernel pipeline on any launch error.
  int perCU = 0;
  hipError_t err = hipOccupancyMaxActiveBlocksPerMultiprocessor(&perCU, fused,
                                                                256, 0);
  int nblk = (err == hipSuccess && perCU > 0) ? perCU * 256 : 512;
  if (nblk > 512) nblk = 512;

  void* args[] = {(void*)&x, (void*)&w_qkv, (void*)&b_qkv, (void*)&w_out,
                  (void*)&b_out, (void*)&out, (void*)&xb, (void*)&wqT,
                  (void*)&woT, (void*)&qb, (void*)&kb, (void*)&vb, (void*)&ao};
  err = hipLaunchCooperativeKernel(fused, dim3(nblk), dim3(256), args, 0,
                                   stream);
  if (err != hipSuccess) {
    (void)hipGetLastError();  // clear sticky error
    prep<<<8192, 256, 0, stream>>>(x, w_qkv, w_out, xb, wqT, woT);
    gemm_qkv<<<dim3(32, 24), 256, 0, stream>>>(xb, wqT, b_qkv, qb, kb, vb,
                                               4096, 3072, 1024);
    attn_fa<<<dim3(16, 2, 16), 256, 0, stream>>>(qb, kb, vb, ao);
    gemm_out<<<dim3(64, 8), 256, 0, stream>>>(ao, woT, b_out, out,
                                              4096, 1024, 1024);
  }
}

// Round 13
// 185.230 us; speedup vs baseline: 2.4771x; 2.4771x over previous
//
#include <hip/hip_runtime.h>
#include <cstdint>

using u16 = unsigned short;
typedef __bf16 bf16x8 __attribute__((ext_vector_type(8)));
typedef __bf16 bf16x4 __attribute__((ext_vector_type(4)));
typedef float f32x4 __attribute__((ext_vector_type(4)));

#define MFMA16(a, b, c) __builtin_amdgcn_mfma_f32_16x16x32_bf16((a), (b), (c), 0, 0, 0)

__device__ __forceinline__ u16 f2bf(float f) {
  union { float f; uint32_t u; } c; c.f = f;
  uint32_t u = c.u;
  u += 0x7fffu + ((u >> 16) & 1u);   // RNE
  return (u16)(u >> 16);
}

#if __has_builtin(__builtin_amdgcn_global_load_lds)
#define GLOAD_LDS16(g, l)                                                      \
  __builtin_amdgcn_global_load_lds(                                            \
      (__attribute__((address_space(1))) void*)(g),                            \
      (__attribute__((address_space(3))) void*)(l), 16, 0, 0)
#else
#define GLOAD_LDS16(g, l) do { *(uint4*)(l) = *(const uint4*)(g); } while (0)
#endif

// ---------------- fused prep: x->bf16, w_qkv^T->bf16, w_out^T->bf16 --------
__global__ __launch_bounds__(256) void prep(
    const float* __restrict__ x, const float* __restrict__ w_qkv,
    const float* __restrict__ w_out, u16* __restrict__ xb,
    u16* __restrict__ wqT, u16* __restrict__ woT) {
  const int bid = blockIdx.x, tid = threadIdx.x;
  if (bid < 4096) {
    int i = (bid * 256 + tid) * 4;
    float4 v = *(const float4*)&x[i];
    ushort4 p;
    p.x = f2bf(v.x); p.y = f2bf(v.y); p.z = f2bf(v.z); p.w = f2bf(v.w);
    *(ushort4*)&xb[i] = p;
    return;
  }
  __shared__ float tile[32][33];
  int t = bid - 4096;
  const float* in;
  u16* outp;
  int C, bx, by;
  if (t < 3072) { in = w_qkv; outp = wqT; C = 3072; bx = (t % 96) * 32; by = (t / 96) * 32; }
  else { t -= 3072; in = w_out; outp = woT; C = 1024; bx = (t % 32) * 32; by = (t / 32) * 32; }
  const int tx = tid & 31, ty = tid >> 5;
#pragma unroll
  for (int r2 = 0; r2 < 4; ++r2)
    tile[ty + r2 * 8][tx] = in[(size_t)(by + ty + r2 * 8) * C + bx + tx];
  __syncthreads();
#pragma unroll
  for (int r2 = 0; r2 < 4; ++r2)
    outp[(size_t)(bx + ty + r2 * 8) * 1024 + by + tx] = f2bf(tile[tx][ty + r2 * 8]);
}

// ------- GEMM 128x192: C = A @ Bt^T + bias, QKV scatter (R12-verified) -----
// grid (32,16) = 512 = 2/CU exact; 24 MFMA : 5 DMA per k-iter.
__global__ __launch_bounds__(256, 2) void gemm_qkv(
    const u16* __restrict__ A, const u16* __restrict__ Bt,
    const float* __restrict__ bias,
    u16* __restrict__ qb, u16* __restrict__ kb, u16* __restrict__ vb) {
  __shared__ u16 As[128 * 32];
  __shared__ u16 Bs[192 * 32];
  const int S = 2048;
  const int tid = threadIdx.x;
  const int m0 = blockIdx.x * 128;
  const int n0 = blockIdx.y * 192;
  const int lane = tid & 63, w = tid >> 6;
  const int quad = lane >> 4, l16 = lane & 15;
  const int wr = w >> 1, wc = w & 1;

  f32x4 acc[4][6] = {};

  const int r0 = tid >> 2, p0 = tid & 3;
  const int c8 = p0 ^ ((r0 >> 1) & 3);
  const u16* ga0 = A + (size_t)(m0 + r0) * 1024 + c8 * 8;
  const u16* ga1 = ga0 + (size_t)64 * 1024;
  const u16* gb0 = Bt + (size_t)(n0 + r0) * 1024 + c8 * 8;
  const u16* gb1 = gb0 + (size_t)64 * 1024;
  const u16* gb2 = gb0 + (size_t)128 * 1024;
  u16* la0 = &As[tid * 8];
  u16* la1 = &As[(tid + 256) * 8];
  u16* lb0 = &Bs[tid * 8];
  u16* lb1 = &Bs[(tid + 256) * 8];
  u16* lb2 = &Bs[(tid + 512) * 8];

  int aoff[4], boff[6];
#pragma unroll
  for (int i = 0; i < 4; ++i) {
    int ra = wr * 64 + i * 16 + l16;
    aoff[i] = (ra * 4 + (quad ^ ((ra >> 1) & 3))) * 8;
  }
#pragma unroll
  for (int j = 0; j < 6; ++j) {
    int rb = wc * 96 + j * 16 + l16;
    boff[j] = (rb * 4 + (quad ^ ((rb >> 1) & 3))) * 8;
  }

  for (int kt = 0; kt < 32; ++kt) {
    __syncthreads();
    const int kk = kt << 5;
    GLOAD_LDS16(ga0 + kk, la0);
    GLOAD_LDS16(ga1 + kk, la1);
    GLOAD_LDS16(gb0 + kk, lb0);
    GLOAD_LDS16(gb1 + kk, lb1);
    GLOAD_LDS16(gb2 + kk, lb2);
    __syncthreads();
    bf16x8 af[4], bfr[6];
#pragma unroll
    for (int i = 0; i < 4; ++i) af[i] = *(const bf16x8*)&As[aoff[i]];
#pragma unroll
    for (int j = 0; j < 6; ++j) bfr[j] = *(const bf16x8*)&Bs[boff[j]];
#pragma unroll
    for (int i = 0; i < 4; ++i)
#pragma unroll
      for (int j = 0; j < 6; ++j)
        acc[i][j] = MFMA16(af[i], bfr[j], acc[i][j]);
  }

#pragma unroll
  for (int i = 0; i < 4; ++i) {
    const int mb = m0 + wr * 64 + i * 16 + quad * 4;
#pragma unroll
    for (int j = 0; j < 6; ++j) {
      const int n = n0 + wc * 96 + j * 16 + l16;
      const float bv = bias[n];
      const int which = n >> 10;      // 0:Q 1:K 2:V (wave-uniform per (wc,j))
      const int hn = n & 1023;
      const int hh = hn >> 6, d = hn & 63;
      const int bb = mb >> 11, s = mb & 2047;
      const int bh = bb * 16 + hh;
      if (which == 2) {
        ushort4 pk;
        pk.x = f2bf(acc[i][j][0] + bv);
        pk.y = f2bf(acc[i][j][1] + bv);
        pk.z = f2bf(acc[i][j][2] + bv);
        pk.w = f2bf(acc[i][j][3] + bv);
        *(ushort4*)&vb[((size_t)bh * 64 + d) * S + s] = pk;  // V transposed
      } else {
        // Q pre-scaled by HD^-0.5 * log2(e): scores land in exp2 domain
        const float sc = (which == 0) ? 0.18033688f : 1.0f;
        u16* dst = (which == 0) ? qb : kb;
#pragma unroll
        for (int r = 0; r < 4; ++r)
          dst[((size_t)bh * S + s + r) * 64 + d] = f2bf((acc[i][j][r] + bv) * sc);
      }
    }
  }
}

// ---------------- GEMM 64x128: out = A @ Bt^T + bias (fp32 out) ----------
__global__ __launch_bounds__(256, 2) void gemm_out(
    const u16* __restrict__ A, const u16* __restrict__ Bt,
    const float* __restrict__ bias, float* __restrict__ outf,
    int M, int N, int K) {
  __shared__ u16 As[64 * 32];
  __shared__ u16 Bs[128 * 32];
  const int tid = threadIdx.x;
  const int m0 = blockIdx.x * 64;
  const int n0 = blockIdx.y * 128;
  const int lane = tid & 63, w = tid >> 6;
  const int quad = lane >> 4, l16 = lane & 15;
  const int wr = w >> 1, wc = w & 1;

  f32x4 acc[2][4] = {};

  const int r0 = tid >> 2, p0 = tid & 3;
  const int c8 = p0 ^ ((r0 >> 1) & 3);
  const u16* ga0 = A + (size_t)(m0 + r0) * K + c8 * 8;
  const u16* gb0 = Bt + (size_t)(n0 + r0) * K + c8 * 8;
  const u16* gb1 = Bt + (size_t)(n0 + r0 + 64) * K + c8 * 8;
  u16* la0 = &As[tid * 8];
  u16* lb0 = &Bs[tid * 8];
  u16* lb1 = &Bs[(tid + 256) * 8];

  int aoff[2], boff[4];
#pragma unroll
  for (int i = 0; i < 2; ++i) {
    int ra = wr * 32 + i * 16 + l16;
    aoff[i] = (ra * 4 + (quad ^ ((ra >> 1) & 3))) * 8;
  }
#pragma unroll
  for (int j = 0; j < 4; ++j) {
    int rb = wc * 64 + j * 16 + l16;
    boff[j] = (rb * 4 + (quad ^ ((rb >> 1) & 3))) * 8;
  }

  const int nIter = K >> 5;
  for (int kt = 0; kt < nIter; ++kt) {
    __syncthreads();
    const int kk = kt << 5;
    GLOAD_LDS16(ga0 + kk, la0);
    GLOAD_LDS16(gb0 + kk, lb0);
    GLOAD_LDS16(gb1 + kk, lb1);
    __syncthreads();
    bf16x8 af[2], bfr[4];
#pragma unroll
    for (int i = 0; i < 2; ++i) af[i] = *(const bf16x8*)&As[aoff[i]];
#pragma unroll
    for (int j = 0; j < 4; ++j) bfr[j] = *(const bf16x8*)&Bs[boff[j]];
#pragma unroll
    for (int i = 0; i < 2; ++i)
#pragma unroll
      for (int j = 0; j < 4; ++j)
        acc[i][j] = MFMA16(af[i], bfr[j], acc[i][j]);
  }

#pragma unroll
  for (int i = 0; i < 2; ++i) {
    const int mb = m0 + wr * 32 + i * 16 + quad * 4;
#pragma unroll
    for (int j = 0; j < 4; ++j) {
      const int n = n0 + wc * 64 + j * 16 + l16;
      const float bv = bias[n];
#pragma unroll
      for (int r = 0; r < 4; ++r)
        outf[(size_t)(mb + r) * N + n] = acc[i][j][r] + bv;
    }
  }
}

// ---------------- flash attention (R4 kernel verbatim) ---------------------
__global__ __launch_bounds__(256, 2) void attn_fa(
    const u16* __restrict__ qg, const u16* __restrict__ kg,
    const u16* __restrict__ vg, u16* __restrict__ o) {
  const int S = 2048, NH = 16;
  const int h = blockIdx.x, b = blockIdx.y, qblk = blockIdx.z;
  const int bh = b * NH + h;
  const int tid = threadIdx.x, w = tid >> 6, lane = tid & 63;
  const int quad = lane >> 4, l16 = lane & 15;

  __shared__ u16 Ks[2][4096];
  __shared__ u16 Vs[2][4096];      // V^T [d][sk]
  __shared__ u16 Ps[4][2048];      // per-wave [32 q][64 k], granule^l16 swizzle

  const int q0 = qblk * 128 + w * 32;
  const u16* qp = qg + ((size_t)bh * S + q0 + l16) * 64 + quad * 8;
  const bf16x8 qf00 = *(const bf16x8*)qp;
  const bf16x8 qf01 = *(const bf16x8*)(qp + 32);
  const bf16x8 qf10 = *(const bf16x8*)(qp + 1024);
  const bf16x8 qf11 = *(const bf16x8*)(qp + 1024 + 32);

  f32x4 accO0[4] = {}, accO1[4] = {};
  f32x4 accL0 = {}, accL1 = {};    // row-sum accumulators (ones-MFMA)

  bf16x8 ones;
#pragma unroll
  for (int i = 0; i < 8; ++i) ones[i] = (__bf16)1.0f;

  const u16* kbase = kg + (size_t)bh * S * 64;
  const u16* vbase = vg + (size_t)bh * 64 * S;

  const int sr0 = tid >> 3, sp0 = tid & 7;
  const int c8s = sp0 ^ (sr0 & 7);
  const u16* kS0 = kbase + (size_t)sr0 * 64 + c8s * 8;
  const u16* kS1 = kbase + (size_t)(sr0 + 32) * 64 + c8s * 8;
  const u16* vS0 = vbase + (size_t)sr0 * S + c8s * 8;
  const u16* vS1 = vbase + (size_t)(sr0 + 32) * S + c8s * 8;

  int koff[4][2];
#pragma unroll
  for (int ct = 0; ct < 4; ++ct) {
    int row = ct * 16 + l16;
    koff[ct][0] = (row * 8 + (quad ^ (row & 7))) * 8;
    koff[ct][1] = (row * 8 + ((quad + 4) ^ (row & 7))) * 8;
  }
  u16* Pw0 = &Ps[w][l16 * 64];          // qt0 row base
  u16* Pw1 = Pw0 + 1024;                // qt1 row base
  int pgx[4];
#pragma unroll
  for (int ct = 0; ct < 4; ++ct) pgx[ct] = ((ct * 4 + quad) ^ l16) * 4;
  const int pr0 = ((quad * 2) ^ l16) * 4;  // frag granules: pr0, ^4, ^32, ^36

  // preload tile 0 into buffer 0
  GLOAD_LDS16(kS0, &Ks[0][tid * 8]);
  GLOAD_LDS16(kS1, &Ks[0][tid * 8 + 2048]);
  GLOAD_LDS16(vS0, &Vs[0][tid * 8]);
  GLOAD_LDS16(vS1, &Vs[0][tid * 8 + 2048]);

  for (int kt = 0; kt < S / 64; ++kt) {
    const int cur = kt & 1;
    __syncthreads();  // drains in-flight glds (issued a full tile ago)
    if (kt + 1 < S / 64) {
      const int nb = cur ^ 1;
      GLOAD_LDS16(kS0 + (size_t)(kt + 1) * 4096, &Ks[nb][tid * 8]);
      GLOAD_LDS16(kS1 + (size_t)(kt + 1) * 4096, &Ks[nb][tid * 8 + 2048]);
      GLOAD_LDS16(vS0 + (kt + 1) * 64, &Vs[nb][tid * 8]);
      GLOAD_LDS16(vS1 + (kt + 1) * 64, &Vs[nb][tid * 8 + 2048]);
    }
    const u16* Kc = Ks[cur];
    const u16* Vc = Vs[cur];

    // ---- S^T = K Q^T ----
    bf16x8 kf0[4], kf1[4];
#pragma unroll
    for (int ct = 0; ct < 4; ++ct) {
      kf0[ct] = *(const bf16x8*)&Kc[koff[ct][0]];
      kf1[ct] = *(const bf16x8*)&Kc[koff[ct][1]];
    }
    f32x4 s0[4] = {}, s1[4] = {};
#pragma unroll
    for (int ct = 0; ct < 4; ++ct) {
      s0[ct] = MFMA16(kf0[ct], qf00, s0[ct]);
      s0[ct] = MFMA16(kf1[ct], qf01, s0[ct]);
      s1[ct] = MFMA16(kf0[ct], qf10, s1[ct]);
      s1[ct] = MFMA16(kf1[ct], qf11, s1[ct]);
    }

    // ---- P = exp2(s), raw v_exp_f32 ----
#pragma unroll
    for (int ct = 0; ct < 4; ++ct)
#pragma unroll
      for (int r = 0; r < 4; ++r) {
        s0[ct][r] = __builtin_amdgcn_exp2f(s0[ct][r]);
        s1[ct][r] = __builtin_amdgcn_exp2f(s1[ct][r]);
      }

    // ---- pack P -> per-wave LDS ----
#pragma unroll
    for (int ct = 0; ct < 4; ++ct) {
      bf16x4 a = {(__bf16)s0[ct][0], (__bf16)s0[ct][1],
                  (__bf16)s0[ct][2], (__bf16)s0[ct][3]};
      *(bf16x4*)&Pw0[pgx[ct]] = a;
      bf16x4 c = {(__bf16)s1[ct][0], (__bf16)s1[ct][1],
                  (__bf16)s1[ct][2], (__bf16)s1[ct][3]};
      *(bf16x4*)&Pw1[pgx[ct]] = c;
    }

    // ---- read P as B-fragments ----
    bf16x4 t0 = *(const bf16x4*)&Pw0[pr0];
    bf16x4 t1 = *(const bf16x4*)&Pw0[pr0 ^ 4];
    bf16x4 t2 = *(const bf16x4*)&Pw0[pr0 ^ 32];
    bf16x4 t3 = *(const bf16x4*)&Pw0[pr0 ^ 36];
    bf16x8 pf00 = __builtin_shufflevector(t0, t1, 0, 1, 2, 3, 4, 5, 6, 7);
    bf16x8 pf01 = __builtin_shufflevector(t2, t3, 0, 1, 2, 3, 4, 5, 6, 7);
    t0 = *(const bf16x4*)&Pw1[pr0];
    t1 = *(const bf16x4*)&Pw1[pr0 ^ 4];
    t2 = *(const bf16x4*)&Pw1[pr0 ^ 32];
    t3 = *(const bf16x4*)&Pw1[pr0 ^ 36];
    bf16x8 pf10 = __builtin_shufflevector(t0, t1, 0, 1, 2, 3, 4, 5, 6, 7);
    bf16x8 pf11 = __builtin_shufflevector(t2, t3, 0, 1, 2, 3, 4, 5, 6, 7);

    // ---- row sums on the matrix pipe ----
    accL0 = MFMA16(ones, pf00, accL0);
    accL0 = MFMA16(ones, pf01, accL0);
    accL1 = MFMA16(ones, pf10, accL1);
    accL1 = MFMA16(ones, pf11, accL1);

    // ---- O^T += V^T P^T ----
#pragma unroll
    for (int ct = 0; ct < 4; ++ct) {
      bf16x8 vf0 = *(const bf16x8*)&Vc[koff[ct][0]];
      bf16x8 vf1 = *(const bf16x8*)&Vc[koff[ct][1]];
      accO0[ct] = MFMA16(vf0, pf00, accO0[ct]);
      accO0[ct] = MFMA16(vf1, pf01, accO0[ct]);
      accO1[ct] = MFMA16(vf0, pf10, accO1[ct]);
      accO1[ct] = MFMA16(vf1, pf11, accO1[ct]);
    }
  }

  const float inv0 = 1.f / accL0[0], inv1 = 1.f / accL1[0];

  const int s0r = q0 + l16, s1r = q0 + 16 + l16;
#pragma unroll
  for (int ct = 0; ct < 4; ++ct) {
    ushort4 pk;
    pk.x = f2bf(accO0[ct][0] * inv0);
    pk.y = f2bf(accO0[ct][1] * inv0);
    pk.z = f2bf(accO0[ct][2] * inv0);
    pk.w = f2bf(accO0[ct][3] * inv0);
    *(ushort4*)&o[(size_t)(b * S + s0r) * 1024 + h * 64 + ct * 16 + quad * 4] = pk;
    pk.x = f2bf(accO1[ct][0] * inv1);
    pk.y = f2bf(accO1[ct][1] * inv1);
    pk.z = f2bf(accO1[ct][2] * inv1);
    pk.w = f2bf(accO1[ct][3] * inv1);
    *(ushort4*)&o[(size_t)(b * S + s1r) * 1024 + h * 64 + ct * 16 + quad * 4] = pk;
  }
}

// ---------------- launch ----------------

extern "C" void kernel_launch(void* const* d_in, const int* in_sizes, int n_in,
                              void* d_out, int out_size, void* d_ws, size_t ws_size,
                              hipStream_t stream) {
  const float* x = (const float*)d_in[0];
  const float* w_qkv = (const float*)d_in[1];
  const float* b_qkv = (const float*)d_in[2];
  const float* w_out = (const float*)d_in[3];
  const float* b_out = (const float*)d_in[4];
  float* out = (float*)d_out;

  u16* xb = (u16*)d_ws;                 // [4096,1024]
  u16* wqT = xb + 4096 * 1024;          // [3072,1024]
  u16* woT = wqT + 3072 * 1024;         // [1024,1024]
  u16* qb = woT + 1024 * 1024;          // [32,2048,64] (pre-scaled)
  u16* kb = qb + 4194304;               // [32,2048,64]
  u16* vb = kb + 4194304;               // [32,64,2048]
  u16* ao = vb + 4194304;               // [4096,1024]

  prep<<<8192, 256, 0, stream>>>(x, w_qkv, w_out, xb, wqT, woT);
  gemm_qkv<<<dim3(32, 16), 256, 0, stream>>>(xb, wqT, b_qkv, qb, kb, vb);
  attn_fa<<<dim3(16, 2, 16), 256, 0, stream>>>(qb, kb, vb, ao);
  gemm_out<<<dim3(64, 8), 256, 0, stream>>>(ao, woT, b_out, out,
                                            4096, 1024, 1024);
}

// Round 14
// 179.974 us; speedup vs baseline: 2.5495x; 1.0292x over previous
//
#include <hip/hip_runtime.h>
#include <cstdint>

using u16 = unsigned short;
typedef __bf16 bf16x8 __attribute__((ext_vector_type(8)));
typedef __bf16 bf16x4 __attribute__((ext_vector_type(4)));
typedef float f32x4 __attribute__((ext_vector_type(4)));

#define MFMA16(a, b, c) __builtin_amdgcn_mfma_f32_16x16x32_bf16((a), (b), (c), 0, 0, 0)

__device__ __forceinline__ u16 f2bf(float f) {
  union { float f; uint32_t u; } c; c.f = f;
  uint32_t u = c.u;
  u += 0x7fffu + ((u >> 16) & 1u);   // RNE
  return (u16)(u >> 16);
}

#if __has_builtin(__builtin_amdgcn_global_load_lds)
#define GLOAD_LDS16(g, l)                                                      \
  __builtin_amdgcn_global_load_lds(                                            \
      (__attribute__((address_space(1))) void*)(g),                            \
      (__attribute__((address_space(3))) void*)(l), 16, 0, 0)
#else
#define GLOAD_LDS16(g, l) do { *(uint4*)(l) = *(const uint4*)(g); } while (0)
#endif

// ---------------- fused prep: x->bf16, w_qkv^T->bf16, w_out^T->bf16 --------
__global__ __launch_bounds__(256) void prep(
    const float* __restrict__ x, const float* __restrict__ w_qkv,
    const float* __restrict__ w_out, u16* __restrict__ xb,
    u16* __restrict__ wqT, u16* __restrict__ woT) {
  const int bid = blockIdx.x, tid = threadIdx.x;
  if (bid < 4096) {
    int i = (bid * 256 + tid) * 4;
    float4 v = *(const float4*)&x[i];
    ushort4 p;
    p.x = f2bf(v.x); p.y = f2bf(v.y); p.z = f2bf(v.z); p.w = f2bf(v.w);
    *(ushort4*)&xb[i] = p;
    return;
  }
  __shared__ float tile[32][33];
  int t = bid - 4096;
  const float* in;
  u16* outp;
  int C, bx, by;
  if (t < 3072) { in = w_qkv; outp = wqT; C = 3072; bx = (t % 96) * 32; by = (t / 96) * 32; }
  else { t -= 3072; in = w_out; outp = woT; C = 1024; bx = (t % 32) * 32; by = (t / 32) * 32; }
  const int tx = tid & 31, ty = tid >> 5;
#pragma unroll
  for (int r2 = 0; r2 < 4; ++r2)
    tile[ty + r2 * 8][tx] = in[(size_t)(by + ty + r2 * 8) * C + bx + tx];
  __syncthreads();
#pragma unroll
  for (int r2 = 0; r2 < 4; ++r2)
    outp[(size_t)(bx + ty + r2 * 8) * 1024 + by + tx] = f2bf(tile[tx][ty + r2 * 8]);
}

// ---------------- GEMM 128x128 (R10, best measured): QKV scatter -----------
// grid (32,24)=768 = 256 CU x 3 resident; launch_bounds(256,3).
__global__ __launch_bounds__(256, 3) void gemm_qkv(
    const u16* __restrict__ A, const u16* __restrict__ Bt,
    const float* __restrict__ bias,
    u16* __restrict__ qb, u16* __restrict__ kb, u16* __restrict__ vb,
    int M, int N, int K) {
  __shared__ u16 As[128 * 32];
  __shared__ u16 Bs[128 * 32];
  const int tid = threadIdx.x;
  const int m0 = blockIdx.x * 128;
  const int n0 = blockIdx.y * 128;
  const int lane = tid & 63, w = tid >> 6;
  const int quad = lane >> 4, l16 = lane & 15;
  const int wr = w >> 1, wc = w & 1;

  f32x4 acc[4][4] = {};

  const int r0 = tid >> 2, p0 = tid & 3;
  const int r1 = r0 + 64;
  const int c8 = p0 ^ ((r0 >> 1) & 3);
  const u16* ga0 = A + (size_t)(m0 + r0) * K + c8 * 8;
  const u16* ga1 = A + (size_t)(m0 + r1) * K + c8 * 8;
  const u16* gb0 = Bt + (size_t)(n0 + r0) * K + c8 * 8;
  const u16* gb1 = Bt + (size_t)(n0 + r1) * K + c8 * 8;
  u16* la0 = &As[tid * 8];
  u16* la1 = &As[(tid + 256) * 8];
  u16* lb0 = &Bs[tid * 8];
  u16* lb1 = &Bs[(tid + 256) * 8];

  int aoff[4], boff[4];
#pragma unroll
  for (int i = 0; i < 4; ++i) {
    int ra = wr * 64 + i * 16 + l16;
    aoff[i] = (ra * 4 + (quad ^ ((ra >> 1) & 3))) * 8;
    int rb = wc * 64 + i * 16 + l16;
    boff[i] = (rb * 4 + (quad ^ ((rb >> 1) & 3))) * 8;
  }

  const int nIter = K >> 5;
  for (int kt = 0; kt < nIter; ++kt) {
    __syncthreads();
    const int kk = kt << 5;
    GLOAD_LDS16(ga0 + kk, la0);
    GLOAD_LDS16(ga1 + kk, la1);
    GLOAD_LDS16(gb0 + kk, lb0);
    GLOAD_LDS16(gb1 + kk, lb1);
    __syncthreads();
    bf16x8 af[4], bfr[4];
#pragma unroll
    for (int i = 0; i < 4; ++i) af[i] = *(const bf16x8*)&As[aoff[i]];
#pragma unroll
    for (int j = 0; j < 4; ++j) bfr[j] = *(const bf16x8*)&Bs[boff[j]];
#pragma unroll
    for (int i = 0; i < 4; ++i)
#pragma unroll
      for (int j = 0; j < 4; ++j)
        acc[i][j] = MFMA16(af[i], bfr[j], acc[i][j]);
  }

  const int S = 2048, NH = 16;
#pragma unroll
  for (int i = 0; i < 4; ++i) {
    const int mb = m0 + wr * 64 + i * 16 + quad * 4;
#pragma unroll
    for (int j = 0; j < 4; ++j) {
      const int n = n0 + wc * 64 + j * 16 + l16;
      const float bv = bias[n];
      const int which = n >> 10;      // 0:Q 1:K 2:V (uniform per block)
      const int hn = n & 1023;
      const int h = hn >> 6, d = hn & 63;
      const int b = mb >> 11, s = mb & 2047;
      const int bh = b * NH + h;
      if (which == 2) {
        ushort4 pk;
        pk.x = f2bf(acc[i][j][0] + bv);
        pk.y = f2bf(acc[i][j][1] + bv);
        pk.z = f2bf(acc[i][j][2] + bv);
        pk.w = f2bf(acc[i][j][3] + bv);
        *(ushort4*)&vb[((size_t)bh * 64 + d) * S + s] = pk;  // V transposed
      } else {
        // Q pre-scaled by HD^-0.5 * log2(e): scores land in exp2 domain
        const float sc = (which == 0) ? 0.18033688f : 1.0f;
        u16* dst = (which == 0) ? qb : kb;
#pragma unroll
        for (int r = 0; r < 4; ++r)
          dst[((size_t)bh * S + s + r) * 64 + d] = f2bf((acc[i][j][r] + bv) * sc);
      }
    }
  }
}

// ---------------- GEMM 64x128: out = A @ Bt^T + bias (fp32 out) ----------
__global__ __launch_bounds__(256, 2) void gemm_out(
    const u16* __restrict__ A, const u16* __restrict__ Bt,
    const float* __restrict__ bias, float* __restrict__ outf,
    int M, int N, int K) {
  __shared__ u16 As[64 * 32];
  __shared__ u16 Bs[128 * 32];
  const int tid = threadIdx.x;
  const int m0 = blockIdx.x * 64;
  const int n0 = blockIdx.y * 128;
  const int lane = tid & 63, w = tid >> 6;
  const int quad = lane >> 4, l16 = lane & 15;
  const int wr = w >> 1, wc = w & 1;

  f32x4 acc[2][4] = {};

  const int r0 = tid >> 2, p0 = tid & 3;
  const int c8 = p0 ^ ((r0 >> 1) & 3);
  const u16* ga0 = A + (size_t)(m0 + r0) * K + c8 * 8;
  const u16* gb0 = Bt + (size_t)(n0 + r0) * K + c8 * 8;
  const u16* gb1 = Bt + (size_t)(n0 + r0 + 64) * K + c8 * 8;
  u16* la0 = &As[tid * 8];
  u16* lb0 = &Bs[tid * 8];
  u16* lb1 = &Bs[(tid + 256) * 8];

  int aoff[2], boff[4];
#pragma unroll
  for (int i = 0; i < 2; ++i) {
    int ra = wr * 32 + i * 16 + l16;
    aoff[i] = (ra * 4 + (quad ^ ((ra >> 1) & 3))) * 8;
  }
#pragma unroll
  for (int j = 0; j < 4; ++j) {
    int rb = wc * 64 + j * 16 + l16;
    boff[j] = (rb * 4 + (quad ^ ((rb >> 1) & 3))) * 8;
  }

  const int nIter = K >> 5;
  for (int kt = 0; kt < nIter; ++kt) {
    __syncthreads();
    const int kk = kt << 5;
    GLOAD_LDS16(ga0 + kk, la0);
    GLOAD_LDS16(gb0 + kk, lb0);
    GLOAD_LDS16(gb1 + kk, lb1);
    __syncthreads();
    bf16x8 af[2], bfr[4];
#pragma unroll
    for (int i = 0; i < 2; ++i) af[i] = *(const bf16x8*)&As[aoff[i]];
#pragma unroll
    for (int j = 0; j < 4; ++j) bfr[j] = *(const bf16x8*)&Bs[boff[j]];
#pragma unroll
    for (int i = 0; i < 2; ++i)
#pragma unroll
      for (int j = 0; j < 4; ++j)
        acc[i][j] = MFMA16(af[i], bfr[j], acc[i][j]);
  }

#pragma unroll
  for (int i = 0; i < 2; ++i) {
    const int mb = m0 + wr * 32 + i * 16 + quad * 4;
#pragma unroll
    for (int j = 0; j < 4; ++j) {
      const int n = n0 + wc * 64 + j * 16 + l16;
      const float bv = bias[n];
#pragma unroll
      for (int r = 0; r < 4; ++r)
        outf[(size_t)(mb + r) * N + n] = acc[i][j][r] + bv;
    }
  }
}

// ---------------- flash attention v8: 128-key tiles, 16 barriers -----------
// Same math/layout as R4 (verified), but K/V double-buffered in 128-key tiles
// (Ks,Vs 16 KB each per buffer; 72 KB total with Ps -> still 2 blocks/CU).
// Each tile computed as two 64-key halves reusing per-wave Ps (same-wave DS
// is in-order). Barrier-drain events: 32 -> 16, each with 2x compute cover.
__global__ __launch_bounds__(256, 2) void attn_fa(
    const u16* __restrict__ qg, const u16* __restrict__ kg,
    const u16* __restrict__ vg, u16* __restrict__ o) {
  const int S = 2048, NH = 16;
  const int h = blockIdx.x, b = blockIdx.y, qblk = blockIdx.z;
  const int bh = b * NH + h;
  const int tid = threadIdx.x, w = tid >> 6, lane = tid & 63;
  const int quad = lane >> 4, l16 = lane & 15;

  __shared__ u16 Ks[2][8192];   // [128 key-rows][8 granules], ^(row&7) swizzle
  __shared__ u16 Vs[2][8192];   // [64 d-rows][16 granules],  ^(row&7) swizzle
  __shared__ u16 Ps[4][2048];   // per-wave [32 q][64 k] (per half)

  const int q0 = qblk * 128 + w * 32;
  const u16* qp = qg + ((size_t)bh * S + q0 + l16) * 64 + quad * 8;
  const bf16x8 qf00 = *(const bf16x8*)qp;
  const bf16x8 qf01 = *(const bf16x8*)(qp + 32);
  const bf16x8 qf10 = *(const bf16x8*)(qp + 1024);
  const bf16x8 qf11 = *(const bf16x8*)(qp + 1024 + 32);

  f32x4 accO0[4] = {}, accO1[4] = {};
  f32x4 accL0 = {}, accL1 = {};    // row-sum accumulators (ones-MFMA)

  bf16x8 ones;
#pragma unroll
  for (int i = 0; i < 8; ++i) ones[i] = (__bf16)1.0f;

  const u16* kbase = kg + (size_t)bh * S * 64;
  const u16* vbase = vg + (size_t)bh * 64 * S;

  // K staging (4 insts/tile): inst seg stages rows seg*32+sr0, phys granule
  // sp0 holds logical granule sp0^(sr0&7). 8 lanes cover a full 128 B row.
  const int sr0 = tid >> 3, sp0 = tid & 7;
  const int c8s = sp0 ^ (sr0 & 7);
  const u16* kSrc = kbase + (size_t)sr0 * 64 + c8s * 8;
  // V staging (4 insts/tile): inst seg stages d-rows seg*16+vr0; phys granule
  // vp0 (of 16) holds logical vp0^(vr0&7); 16 lanes cover 256 B of a row.
  const int vr0 = tid >> 4, vp0 = tid & 15;
  const int vgs = vp0 ^ (vr0 & 7);
  const u16* vSrc = vbase + (size_t)vr0 * S + vgs * 8;

  // fragment granule swizzles (row&7 == l16&7 for all slabs/halves)
  const int kgA = (quad ^ (l16 & 7)) * 8;
  const int kgB = ((quad + 4) ^ (l16 & 7)) * 8;
  int vgA[2], vgB[2];
#pragma unroll
  for (int hh = 0; hh < 2; ++hh) {
    vgA[hh] = (hh * 8 + (quad ^ (l16 & 7))) * 8;
    vgB[hh] = (hh * 8 + ((quad + 4) ^ (l16 & 7))) * 8;
  }

  u16* Pw0 = &Ps[w][l16 * 64];          // qt0 row base
  u16* Pw1 = Pw0 + 1024;                // qt1 row base
  int pgx[4];
#pragma unroll
  for (int ct = 0; ct < 4; ++ct) pgx[ct] = ((ct * 4 + quad) ^ l16) * 4;
  const int pr0 = ((quad * 2) ^ l16) * 4;  // frag granules: pr0, ^4, ^32, ^36

  // preload tile 0 into buffer 0
#pragma unroll
  for (int seg = 0; seg < 4; ++seg) {
    GLOAD_LDS16(kSrc + (size_t)seg * 32 * 64, &Ks[0][(seg * 256 + tid) * 8]);
    GLOAD_LDS16(vSrc + (size_t)seg * 16 * S, &Vs[0][(seg * 256 + tid) * 8]);
  }

  for (int kt = 0; kt < 16; ++kt) {
    const int cur = kt & 1;
    __syncthreads();  // drains in-flight glds (issued a full 128-key tile ago)
    if (kt + 1 < 16) {
      const int nb = cur ^ 1;
#pragma unroll
      for (int seg = 0; seg < 4; ++seg) {
        GLOAD_LDS16(kSrc + (size_t)((kt + 1) * 128 + seg * 32) * 64,
                    &Ks[nb][(seg * 256 + tid) * 8]);
        GLOAD_LDS16(vSrc + (size_t)seg * 16 * S + (kt + 1) * 128,
                    &Vs[nb][(seg * 256 + tid) * 8]);
      }
    }
    const u16* Kc = Ks[cur];
    const u16* Vc = Vs[cur];

#pragma unroll
    for (int hh = 0; hh < 2; ++hh) {
      // ---- S^T = K Q^T ----
      bf16x8 kf0[4], kf1[4];
#pragma unroll
      for (int ct = 0; ct < 4; ++ct) {
        const int rb = (hh * 64 + ct * 16 + l16) * 64;
        kf0[ct] = *(const bf16x8*)&Kc[rb + kgA];
        kf1[ct] = *(const bf16x8*)&Kc[rb + kgB];
      }
      f32x4 s0[4] = {}, s1[4] = {};
#pragma unroll
      for (int ct = 0; ct < 4; ++ct) {
        s0[ct] = MFMA16(kf0[ct], qf00, s0[ct]);
        s0[ct] = MFMA16(kf1[ct], qf01, s0[ct]);
        s1[ct] = MFMA16(kf0[ct], qf10, s1[ct]);
        s1[ct] = MFMA16(kf1[ct], qf11, s1[ct]);
      }

      // ---- P = exp2(s), raw v_exp_f32 ----
#pragma unroll
      for (int ct = 0; ct < 4; ++ct)
#pragma unroll
        for (int r = 0; r < 4; ++r) {
          s0[ct][r] = __builtin_amdgcn_exp2f(s0[ct][r]);
          s1[ct][r] = __builtin_amdgcn_exp2f(s1[ct][r]);
        }

      // ---- pack P -> per-wave LDS (reused across halves; same-wave order) --
#pragma unroll
      for (int ct = 0; ct < 4; ++ct) {
        bf16x4 a = {(__bf16)s0[ct][0], (__bf16)s0[ct][1],
                    (__bf16)s0[ct][2], (__bf16)s0[ct][3]};
        *(bf16x4*)&Pw0[pgx[ct]] = a;
        bf16x4 c = {(__bf16)s1[ct][0], (__bf16)s1[ct][1],
                    (__bf16)s1[ct][2], (__bf16)s1[ct][3]};
        *(bf16x4*)&Pw1[pgx[ct]] = c;
      }

      // ---- read P as B-fragments ----
      bf16x4 t0 = *(const bf16x4*)&Pw0[pr0];
      bf16x4 t1 = *(const bf16x4*)&Pw0[pr0 ^ 4];
      bf16x4 t2 = *(const bf16x4*)&Pw0[pr0 ^ 32];
      bf16x4 t3 = *(const bf16x4*)&Pw0[pr0 ^ 36];
      bf16x8 pf00 = __builtin_shufflevector(t0, t1, 0, 1, 2, 3, 4, 5, 6, 7);
      bf16x8 pf01 = __builtin_shufflevector(t2, t3, 0, 1, 2, 3, 4, 5, 6, 7);
      t0 = *(const bf16x4*)&Pw1[pr0];
      t1 = *(const bf16x4*)&Pw1[pr0 ^ 4];
      t2 = *(const bf16x4*)&Pw1[pr0 ^ 32];
      t3 = *(const bf16x4*)&Pw1[pr0 ^ 36];
      bf16x8 pf10 = __builtin_shufflevector(t0, t1, 0, 1, 2, 3, 4, 5, 6, 7);
      bf16x8 pf11 = __builtin_shufflevector(t2, t3, 0, 1, 2, 3, 4, 5, 6, 7);

      // ---- row sums on the matrix pipe ----
      accL0 = MFMA16(ones, pf00, accL0);
      accL0 = MFMA16(ones, pf01, accL0);
      accL1 = MFMA16(ones, pf10, accL1);
      accL1 = MFMA16(ones, pf11, accL1);

      // ---- O^T += V^T P^T ----
#pragma unroll
      for (int ct = 0; ct < 4; ++ct) {
        const int rb = (ct * 16 + l16) * 128;
        bf16x8 vf0 = *(const bf16x8*)&Vc[rb + vgA[hh]];
        bf16x8 vf1 = *(const bf16x8*)&Vc[rb + vgB[hh]];
        accO0[ct] = MFMA16(vf0, pf00, accO0[ct]);
        accO0[ct] = MFMA16(vf1, pf01, accO0[ct]);
        accO1[ct] = MFMA16(vf0, pf10, accO1[ct]);
        accO1[ct] = MFMA16(vf1, pf11, accO1[ct]);
      }
    }
  }

  const float inv0 = 1.f / accL0[0], inv1 = 1.f / accL1[0];

  const int s0r = q0 + l16, s1r = q0 + 16 + l16;
#pragma unroll
  for (int ct = 0; ct < 4; ++ct) {
    ushort4 pk;
    pk.x = f2bf(accO0[ct][0] * inv0);
    pk.y = f2bf(accO0[ct][1] * inv0);
    pk.z = f2bf(accO0[ct][2] * inv0);
    pk.w = f2bf(accO0[ct][3] * inv0);
    *(ushort4*)&o[(size_t)(b * S + s0r) * 1024 + h * 64 + ct * 16 + quad * 4] = pk;
    pk.x = f2bf(accO1[ct][0] * inv1);
    pk.y = f2bf(accO1[ct][1] * inv1);
    pk.z = f2bf(accO1[ct][2] * inv1);
    pk.w = f2bf(accO1[ct][3] * inv1);
    *(ushort4*)&o[(size_t)(b * S + s1r) * 1024 + h * 64 + ct * 16 + quad * 4] = pk;
  }
}

// ---------------- launch ----------------

extern "C" void kernel_launch(void* const* d_in, const int* in_sizes, int n_in,
                              void* d_out, int out_size, void* d_ws, size_t ws_size,
                              hipStream_t stream) {
  const float* x = (const float*)d_in[0];
  const float* w_qkv = (const float*)d_in[1];
  const float* b_qkv = (const float*)d_in[2];
  const float* w_out = (const float*)d_in[3];
  const float* b_out = (const float*)d_in[4];
  float* out = (float*)d_out;

  u16* xb = (u16*)d_ws;                 // [4096,1024]
  u16* wqT = xb + 4096 * 1024;          // [3072,1024]
  u16* woT = wqT + 3072 * 1024;         // [1024,1024]
  u16* qb = woT + 1024 * 1024;          // [32,2048,64] (pre-scaled)
  u16* kb = qb + 4194304;               // [32,2048,64]
  u16* vb = kb + 4194304;               // [32,64,2048]
  u16* ao = vb + 4194304;               // [4096,1024]

  prep<<<8192, 256, 0, stream>>>(x, w_qkv, w_out, xb, wqT, woT);
  gemm_qkv<<<dim3(32, 24), 256, 0, stream>>>(xb, wqT, b_qkv, qb, kb, vb,
                                             4096, 3072, 1024);
  attn_fa<<<dim3(16, 2, 16), 256, 0, stream>>>(qb, kb, vb, ao);
  gemm_out<<<dim3(64, 8), 256, 0, stream>>>(ao, woT, b_out, out,
                                            4096, 1024, 1024);
}